// Round 10
// baseline (2753.087 us; speedup 1.0000x reference)
//
#include <hip/hip_runtime.h>
#include <cstdint>
#include <cstddef>

#define D_MODEL 1024
#define D_STATE 16
#define E_DIM   2048
#define SEQ     4096
#define M_ROWS  16384

typedef unsigned short u16;
typedef unsigned int   u32;
typedef __attribute__((ext_vector_type(8))) short short8;   // 8 bf16 = 4 VGPRs
typedef __attribute__((ext_vector_type(4))) float f32x4;

__device__ __forceinline__ u16 f2bf(float f) {
    u32 u = __float_as_uint(f);
    u32 r = (u + 0x7fffu + ((u >> 16) & 1u)) >> 16;   // RNE
    return (u16)r;
}
__device__ __forceinline__ float bf2f(u16 h) {
    return __uint_as_float(((u32)h) << 16);
}

// ---------------------------------------------------------------------------
// PACKED TILE LAYOUT: every GEMM operand is stored as fragment-linear 128x64
// bf16 tiles (8192 u16). Chunk c (0..1023, 16 B each): msub=c>>7,
// step=(c>>6)&1, ell=c&63 -> row = msub*16+(ell&15),
// cols = (step*4 + (ell>>4))*8 .. +7.  A lane's MFMA fragment (sub, step) is
// the 16 contiguous bytes at tile_base + ((sub*2+step)*64 + lane)*8 u16 --
// so fragments are loaded DIRECTLY global->VGPR, fully coalesced.
// Tile (Mt, Kt) of an [M, K] operand lives at ((Mt*(K/64) + Kt) * 8192).
// ---------------------------------------------------------------------------
#define HC_STR 17   // padded float stride for epilogue H/C tiles

// packed elementwise offset for XCp (K-dim = E_DIM = 2048, 32 k-tiles)
__device__ __forceinline__ size_t xcp_off(int m, int n) {
    int Mt = m >> 7, mr = m & 127;
    int Kt = n >> 6, nt = n & 63;
    int c16 = nt >> 3;
    int c = (mr >> 4) * 128 + (c16 >> 2) * 64 + (c16 & 3) * 16 + (mr & 15);
    return ((size_t)Mt * 32 + Kt) * 8192 + (size_t)c * 8 + (nt & 7);
}

// ---------------------------------------------------------------------------
// MFMA GEMM on packed operands. C[M,N] = A[M,K] @ B[N,K]^T.
//
// R9: DEDUPLICATED TRAFFIC -- 128x128 PER WAVE, waves stacked 4x1 in M.
// R5/R7/R8 (depth 2/1/4 -> 308/333/305us) + arithmetic: per CU each GEMM
// moved 8 blocks x 1MB (A,B each loaded TWICE by the 2x2 wave grid) in
// ~305us = ~11 B/cy/CU ~= 7 TB/s chip -- a vector-memory THROUGHPUT
// ceiling, not latency (explains depth-insensitivity and flat MfmaUtil 9%).
// Fix: block = 512x128 output, 4 waves each owning a PRIVATE 128-row strip
// (A dedup: each packed A tile read once; B read 4x/block but amortized) ->
// 32 B per output vs 64, total L1 traffic per GEMM 2.1 -> 1.05 GB.
// acc 8x8 f32x4 = 256 VGPR + 4x8 short8 frags = 128 VGPR (~410 total,
// launch_bounds(256,1)). Same accumulation order -> bit-identical output.
//
// XCD swizzle: L%8 ~ XCD; XCD owns contiguous m-strips.
// MODE 0: out bf16 row-major = acc + bias   (-> XP)
// MODE 1: gate: XCp <- sigmoid(acc+bias) * (H@C^T + Dp*XCp), packed in-place
// MODE 2: out fp32 row-major = acc + bias   (-> final out)
// ---------------------------------------------------------------------------
template <int MODE>
__global__ __launch_bounds__(256, 1)
void mfma_gemm(const u16* __restrict__ Ag, const u16* __restrict__ Bg,
               int K, int Nst,
               const float* __restrict__ bias,
               u16* __restrict__ outb, float* __restrict__ outf,
               const float* __restrict__ Hm, const float* __restrict__ Cm,
               const float* __restrict__ Dp, u16* __restrict__ XCp)
{
    const int t     = threadIdx.x;
    const int lane  = t & 63;
    const int w     = t >> 6;
    const int col_l = lane & 15;
    const int quad  = lane >> 4;

    // XCD-aware swizzle (block->XCD ~ L%8): XCD owns contiguous m-strips.
    const int L = blockIdx.y * gridDim.x + blockIdx.x;
    const int xcd = L & 7, g = L >> 3;
    const int ntile  = g % gridDim.x;
    const int mtileB = xcd * (gridDim.y >> 3) + g / gridDim.x;  // 512-row strip
    const int bmB = mtileB * 512;
    const int bm  = bmB + w * 128;      // this wave's 128-row strip
    const int bn  = ntile * 128;

    const int KT = K >> 6;
    // wave-private A packed tile (Mt = mtileB*4 + w); B tile shared by waves
    const u16* aw = Ag + ((size_t)(mtileB * 4 + w) * KT) * 8192 + (size_t)lane * 8;
    const u16* bw = Bg + (size_t)ntile * KT * 8192 + (size_t)lane * 8;

    f32x4 acc[8][8] = {};   // 128x128 per wave: 64 16x16 frags

    auto ldf = [&](short8* da, short8* db, size_t off, int step) {
#pragma unroll
        for (int i = 0; i < 8; ++i) {
            da[i] = *(const short8*)(aw + off + (size_t)((i * 2 + step) * 512));
            db[i] = *(const short8*)(bw + off + (size_t)((i * 2 + step) * 512));
        }
    };
    auto mm = [&](short8* a8, short8* b8) {
#pragma unroll
        for (int i = 0; i < 8; ++i)
#pragma unroll
            for (int j = 0; j < 8; ++j)
                acc[i][j] = __builtin_amdgcn_mfma_f32_16x16x32_bf16(
                    a8[i], b8[j], acc[i][j], 0, 0, 0);
    };

    // depth-1 register ping-pong: 64 MFMA (~310cy) between refill and reuse
    short8 A0[8], B0[8], A1[8], B1[8];
    ldf(A0, B0, 0, 0);
    ldf(A1, B1, 0, 1);
    size_t off = 0;
    for (int kt = 0; kt < KT; ++kt) {
        const bool p = kt + 1 < KT;
        mm(A0, B0); if (p) ldf(A0, B0, off + 8192, 0);
        mm(A1, B1); if (p) ldf(A1, B1, off + 8192, 1);
        off += 8192;
    }

    // C/D layout: col = lane&15, row = quad*4 + reg   [verified m89/m91]
    if (MODE == 0) {
#pragma unroll
        for (int j = 0; j < 8; ++j) {
            int n = bn + j * 16 + col_l;
            float bv = bias[n];
#pragma unroll
            for (int i = 0; i < 8; ++i) {
                int mb = bm + i * 16 + quad * 4;
#pragma unroll
                for (int p = 0; p < 4; ++p)
                    outb[(size_t)(mb + p) * Nst + n] = f2bf(acc[i][j][p] + bv);
            }
        }
    } else if (MODE == 1) {
        __shared__ float Hs[512 * HC_STR];   // 34.8 KB
        __shared__ float Cs[128 * HC_STR];   //  8.7 KB
        for (int idx = t; idx < 512 * D_STATE; idx += 256)
            Hs[(idx >> 4) * HC_STR + (idx & 15)] =
                Hm[((size_t)bmB + (idx >> 4)) * D_STATE + (idx & 15)];
        for (int idx = t; idx < 128 * D_STATE; idx += 256)
            Cs[(idx >> 4) * HC_STR + (idx & 15)] =
                Cm[((size_t)(bn + (idx >> 4))) * D_STATE + (idx & 15)];
        __syncthreads();
#pragma unroll
        for (int i = 0; i < 8; ++i) {
            int mlp = w * 128 + i * 16 + quad * 4;   // local row in block
#pragma unroll
            for (int p = 0; p < 4; ++p) {
                int row = mlp + p;
                float hrow[D_STATE];
#pragma unroll
                for (int s = 0; s < D_STATE; ++s)
                    hrow[s] = Hs[row * HC_STR + s];
#pragma unroll
                for (int j = 0; j < 8; ++j) {
                    int nl = j * 16 + col_l;
                    int n = bn + nl;
                    float z = acc[i][j][p] + bias[n];
                    float sig = 1.f / (1.f + __expf(-z));
                    float dot = 0.f;
#pragma unroll
                    for (int s = 0; s < D_STATE; ++s)
                        dot += hrow[s] * Cs[nl * HC_STR + s];
                    // packed in-place RMW: read & write the SAME address
                    size_t offx = xcp_off(bmB + row, n);
                    float xc = bf2f(XCp[offx]);
                    XCp[offx] = f2bf(sig * (dot + Dp[n] * xc));
                }
            }
        }
    } else {
#pragma unroll
        for (int j = 0; j < 8; ++j) {
            int n = bn + j * 16 + col_l;
            float bv = bias[n];
#pragma unroll
            for (int i = 0; i < 8; ++i) {
                int mb = bm + i * 16 + quad * 4;
#pragma unroll
                for (int p = 0; p < 4; ++p)
                    outf[(size_t)(mb + p) * Nst + n] = acc[i][j][p] + bv;
            }
        }
    }
}

// ---------------------------------------------------------------------------
// pack x fp32 [16384,1024] -> packed bf16 tiles (K-dim 1024, 16 k-tiles)
// ---------------------------------------------------------------------------
__global__ __launch_bounds__(256)
void pack_x_kernel(const float* __restrict__ x, u16* __restrict__ xp)
{
    const int Kt = blockIdx.x;   // 0..15
    const int Mt = blockIdx.y;   // 0..127
    const int t  = threadIdx.x;
    u16* dst = xp + ((size_t)Mt * 16 + Kt) * 8192;
#pragma unroll
    for (int i = 0; i < 4; ++i) {
        int c   = i * 256 + t;
        int ell = c & 63;
        int row = Mt * 128 + (c >> 7) * 16 + (ell & 15);
        int col = Kt * 64 + (((c >> 6) & 1) * 4 + (ell >> 4)) * 8;
        const float4* src = (const float4*)&x[(size_t)row * D_MODEL + col];
        float4 a = src[0], b = src[1];
        alignas(16) u16 o[8] = {f2bf(a.x), f2bf(a.y), f2bf(a.z), f2bf(a.w),
                                f2bf(b.x), f2bf(b.y), f2bf(b.z), f2bf(b.w)};
        *(short8*)(dst + c * 8) = *(const short8*)o;
    }
}

// ---------------------------------------------------------------------------
// pack W^T: src W [K, Wstride] fp32 (cols colOff..colOff+Nt*128) -> packed
// bf16 tiles of B = W^T [N, K].
// ---------------------------------------------------------------------------
__global__ __launch_bounds__(256)
void pack_w_kernel(const float* __restrict__ W, u16* __restrict__ out,
                   int Wstride, int colOff, int KT)
{
    const int Kt = blockIdx.x;
    const int Nt = blockIdx.y;
    const int t  = threadIdx.x;
    u16* dst = out + ((size_t)Nt * KT + Kt) * 8192;
#pragma unroll
    for (int i = 0; i < 4; ++i) {
        int c    = i * 256 + t;
        int ell  = c & 63;
        int nrow = Nt * 128 + (c >> 7) * 16 + (ell & 15);
        int kcol = Kt * 64 + (((c >> 6) & 1) * 4 + (ell >> 4)) * 8;
        alignas(16) u16 o[8];
#pragma unroll
        for (int q = 0; q < 8; ++q)
            o[q] = f2bf(W[(size_t)(kcol + q) * Wstride + colOff + nrow]);
        *(short8*)(dst + c * 8) = *(const short8*)o;
    }
}

// ---------------------------------------------------------------------------
// causal depthwise conv (taps=4): XP row-major bf16 -> XCp PACKED bf16.
// block per (k-tile, m-tile); writes are fully linear per tile.
// ---------------------------------------------------------------------------
__global__ __launch_bounds__(256)
void conv_kernel(const u16* __restrict__ XP, const float* __restrict__ conv_w,
                 const float* __restrict__ conv_b, u16* __restrict__ XCp)
{
    const int Kt = blockIdx.x;   // 0..31
    const int Mt = blockIdx.y;   // 0..127
    const int t  = threadIdx.x;
    u16* dst = XCp + ((size_t)Mt * 32 + Kt) * 8192;
#pragma unroll
    for (int i = 0; i < 4; ++i) {
        int c   = i * 256 + t;
        int ell = c & 63;
        int mr  = (c >> 7) * 16 + (ell & 15);
        int e   = Kt * 64 + (((c >> 6) & 1) * 4 + (ell >> 4)) * 8;
        int m   = Mt * 128 + mr;
        int l   = m & (SEQ - 1);
        float acc[8];
        {
            float4 c0 = *(const float4*)&conv_b[e];
            float4 c1 = *(const float4*)&conv_b[e + 4];
            acc[0] = c0.x; acc[1] = c0.y; acc[2] = c0.z; acc[3] = c0.w;
            acc[4] = c1.x; acc[5] = c1.y; acc[6] = c1.z; acc[7] = c1.w;
        }
#pragma unroll
        for (int k = 0; k < 4; ++k) {
            if (l - 3 + k >= 0) {
                const short8 xv = *(const short8*)&XP[(size_t)(m - 3 + k) * E_DIM + e];
#pragma unroll
                for (int j = 0; j < 8; ++j)
                    acc[j] += bf2f((u16)xv[j]) * conv_w[(size_t)(e + j) * 4 + k];
            }
        }
        alignas(16) u16 o[8];
#pragma unroll
        for (int j = 0; j < 8; ++j) o[j] = f2bf(acc[j]);
        *(short8*)(dst + c * 8) = *(const short8*)o;
    }
}

// ---------------------------------------------------------------------------
// R5: U partials. block per (Kt-pair kp, Mt); thread t owns row rr=t>>1,
// col-half z=t&1, reads the 8 CONTIGUOUS chunks of its row in each packed
// tile (wave = 4x256 B contiguous segments per q-step -> full line
// utilization). Pair-reduce via one shfl_xor(1); partials Up[kp][m][s]
// summed by u_reduce_kernel. Deterministic; no LDS.
// ---------------------------------------------------------------------------
__global__ __launch_bounds__(256)
void u_part_kernel(const u16* __restrict__ XCp, const float* __restrict__ Amat,
                   float* __restrict__ Up)
{
    const int kp = blockIdx.x;   // 0..15 (K-tile pair)
    const int Mt = blockIdx.y;   // 0..127
    const int t  = threadIdx.x;
    const int rr = t >> 1;       // row within tile, 0..127
    const int z  = t & 1;        // col-half (step)
    const int msub = rr >> 4, r = rr & 15;

    float acc[16];
#pragma unroll
    for (int s = 0; s < 16; ++s) acc[s] = 0.f;

#pragma unroll
    for (int kk = 0; kk < 2; ++kk) {
        const int Kt = kp * 2 + kk;
        const u16* tile = XCp + ((size_t)Mt * 32 + Kt) * 8192;
#pragma unroll
        for (int q = 0; q < 4; ++q) {
            const int c = msub * 128 + z * 64 + q * 16 + r;
            const short8 xv = *(const short8*)(tile + (size_t)c * 8);
            const int e0 = Kt * 64 + (z * 4 + q) * 8;
#pragma unroll
            for (int j = 0; j < 8; ++j) {
                float xq = bf2f((u16)xv[j]);
                const float4* ar = (const float4*)&Amat[(size_t)(e0 + j) * D_STATE];
#pragma unroll
                for (int s4 = 0; s4 < 4; ++s4) {
                    float4 a = ar[s4];
                    acc[s4 * 4 + 0] += xq * a.x; acc[s4 * 4 + 1] += xq * a.y;
                    acc[s4 * 4 + 2] += xq * a.z; acc[s4 * 4 + 3] += xq * a.w;
                }
            }
        }
    }
    // combine the two col-halves (partner lane = t^1, same row)
#pragma unroll
    for (int s = 0; s < 16; ++s) acc[s] += __shfl_xor(acc[s], 1);

    if (z == 0) {
        const int m = Mt * 128 + rr;
        float4* dst = (float4*)&Up[((size_t)kp * M_ROWS + m) * D_STATE];
        dst[0] = make_float4(acc[0], acc[1], acc[2], acc[3]);
        dst[1] = make_float4(acc[4], acc[5], acc[6], acc[7]);
        dst[2] = make_float4(acc[8], acc[9], acc[10], acc[11]);
        dst[3] = make_float4(acc[12], acc[13], acc[14], acc[15]);
    }
}

// U[m,s] = sum_kp Up[kp][m][s]   (16 coalesced slices, float4-vectorized)
__global__ __launch_bounds__(256)
void u_reduce_kernel(const float* __restrict__ Up, float* __restrict__ U)
{
    const int idx = blockIdx.x * 256 + threadIdx.x;   // 65536 float4 elems
    const float4* src = (const float4*)Up;
    float4 s = src[idx];
#pragma unroll
    for (int kp = 1; kp < 16; ++kp) {
        float4 v = src[(size_t)kp * (M_ROWS * D_STATE / 4) + idx];
        s.x += v.x; s.y += v.y; s.z += v.z; s.w += v.w;
    }
    ((float4*)U)[idx] = s;
}

// ---------------------------------------------------------------------------
// sequential scan: h_l = tanh(U_l + h_{l-1}), 64 chains.
// Chunked by 8 with FULLY-UNROLLED static-index arrays (stay in VGPRs).
// ---------------------------------------------------------------------------
__global__ __launch_bounds__(64)
void scan_kernel(const float* __restrict__ U, float* __restrict__ H)
{
    const int t = threadIdx.x;
    const int b = t >> 4;
    const int s = t & 15;
    const float* u = U + (size_t)b * SEQ * D_STATE + s;
    float*       h = H + (size_t)b * SEQ * D_STATE + s;

    float cur[8], nxt[8];
#pragma unroll
    for (int j = 0; j < 8; ++j) cur[j] = u[(size_t)j * D_STATE];

    float hv = 0.f;
    for (int l0 = 0; l0 < SEQ; l0 += 8) {
        if (l0 + 8 < SEQ) {
#pragma unroll
            for (int j = 0; j < 8; ++j)
                nxt[j] = u[(size_t)(l0 + 8 + j) * D_STATE];
        }
#pragma unroll
        for (int j = 0; j < 8; ++j) {
            float ex = __expf(2.f * (cur[j] + hv));
            hv = 1.f - 2.f / (ex + 1.f);
            h[(size_t)(l0 + j) * D_STATE] = hv;
        }
#pragma unroll
        for (int j = 0; j < 8; ++j) cur[j] = nxt[j];
    }
}

// ---------------------------------------------------------------------------
extern "C" void kernel_launch(void* const* d_in, const int* in_sizes, int n_in,
                              void* d_out, int out_size, void* d_ws, size_t ws_size,
                              hipStream_t stream)
{
    const float* x      = (const float*)d_in[0];
    const float* W_in   = (const float*)d_in[1];
    const float* b_in   = (const float*)d_in[2];
    const float* conv_w = (const float*)d_in[3];
    const float* conv_b = (const float*)d_in[4];
    const float* Amat   = (const float*)d_in[5];
    const float* Cmat   = (const float*)d_in[6];
    const float* Dp     = (const float*)d_in[7];
    const float* W_out  = (const float*)d_in[8];
    const float* b_out  = (const float*)d_in[9];
    float* out = (float*)d_out;

    // workspace layout (132.1 MB total; 136 MB proven safe)
    char* ws = (char*)d_ws;
    u16*   xbp  = (u16*)(ws);                    // 33.55 MB packed x
    u16*   Wp0  = (u16*)(ws +  33554432);        //  4.19 MB packed W_in[:, :2048]^T
    u16*   Wp1  = (u16*)(ws +  37748736);        //  4.19 MB packed W_in[:, 2048:]^T
    u16*   Wp2  = (u16*)(ws +  41943040);        //  4.19 MB packed W_out^T
    u16*   XCp  = (u16*)(ws +  46137344);        // 67.11 MB packed x_conv
    float* U    = (float*)(ws + 113246208);      //  1.05 MB
    float* H    = (float*)(ws + 114294784);      //  1.05 MB
    float* Up   = (float*)(ws + 115343360);      // 16.78 MB U partials (16x)
    u16*   XP   = (u16*)d_out;  // x_proj bf16 in d_out (67.1 MB), dead after conv

    // 1) pack inputs
    pack_x_kernel<<<dim3(16, 128), 256, 0, stream>>>(x, xbp);
    pack_w_kernel<<<dim3(16, 16), 256, 0, stream>>>(W_in, Wp0, 2 * E_DIM, 0, 16);
    pack_w_kernel<<<dim3(16, 16), 256, 0, stream>>>(W_in, Wp1, 2 * E_DIM, E_DIM, 16);
    pack_w_kernel<<<dim3(32, 8), 256, 0, stream>>>(W_out, Wp2, D_MODEL, 0, 32);

    // 2) XP = bf16(x @ W_in[:, :2048] + b_in)   (row-major, -> d_out)
    mfma_gemm<0><<<dim3(16, 32), 256, 0, stream>>>(
        xbp, Wp0, D_MODEL, E_DIM, b_in, XP, nullptr, nullptr, nullptr, nullptr, nullptr);

    // 3) XCp = packed bf16(causal_conv(XP) + conv_b)
    conv_kernel<<<dim3(32, 128), 256, 0, stream>>>(XP, conv_w, conv_b, XCp);

    // 4) U = XC @ A  (partials + reduce); 5) scan -> H
    u_part_kernel<<<dim3(16, 128), 256, 0, stream>>>(XCp, Amat, Up);
    u_reduce_kernel<<<256, 256, 0, stream>>>(Up, U);
    scan_kernel<<<1, 64, 0, stream>>>(U, H);

    // 6) XCp <- sigmoid(x @ W_in[:, 2048:] + b_in[2048:]) * (H@C^T + Dp*XCp)
    mfma_gemm<1><<<dim3(16, 32), 256, 0, stream>>>(
        xbp, Wp1, D_MODEL, 0, b_in + E_DIM, nullptr, nullptr, H, Cmat, Dp, XCp);

    // 7) out = XC @ W_out + b_out   (fp32, row-major)
    mfma_gemm<2><<<dim3(8, 32), 256, 0, stream>>>(
        XCp, Wp2, E_DIM, D_MODEL, b_out, nullptr, out, nullptr, nullptr, nullptr, nullptr);
}

// Round 12
// 1288.462 us; speedup vs baseline: 2.1367x; 2.1367x over previous
//
#include <hip/hip_runtime.h>
#include <cstdint>
#include <cstddef>

#define D_MODEL 1024
#define D_STATE 16
#define E_DIM   2048
#define SEQ     4096
#define M_ROWS  16384

typedef unsigned short u16;
typedef unsigned int   u32;
typedef __attribute__((ext_vector_type(8))) short short8;   // 8 bf16 = 4 VGPRs
typedef __attribute__((ext_vector_type(4))) float f32x4;

__device__ __forceinline__ u16 f2bf(float f) {
    u32 u = __float_as_uint(f);
    u32 r = (u + 0x7fffu + ((u >> 16) & 1u)) >> 16;   // RNE
    return (u16)r;
}
__device__ __forceinline__ float bf2f(u16 h) {
    return __uint_as_float(((u32)h) << 16);
}

// ---------------------------------------------------------------------------
// PACKED TILE LAYOUT: every GEMM operand is stored as fragment-linear 128x64
// bf16 tiles (8192 u16). Chunk c (0..1023, 16 B each): msub=c>>7,
// step=(c>>6)&1, ell=c&63 -> row = msub*16+(ell&15),
// cols = (step*4 + (ell>>4))*8 .. +7.  A lane's MFMA fragment (sub, step) is
// the 16 contiguous bytes at tile_base + ((sub*2+step)*64 + lane)*8 u16 --
// so fragments are loaded DIRECTLY global->VGPR, fully coalesced.
// Tile (Mt, Kt) of an [M, K] operand lives at ((Mt*(K/64) + Kt) * 8192).
// ---------------------------------------------------------------------------
#define HC_STR 17   // padded float stride for epilogue H/C tiles

// packed elementwise offset for XCp (K-dim = E_DIM = 2048, 32 k-tiles)
__device__ __forceinline__ size_t xcp_off(int m, int n) {
    int Mt = m >> 7, mr = m & 127;
    int Kt = n >> 6, nt = n & 63;
    int c16 = nt >> 3;
    int c = (mr >> 4) * 128 + (c16 >> 2) * 64 + (c16 & 3) * 16 + (mr & 15);
    return ((size_t)Mt * 32 + Kt) * 8192 + (size_t)c * 8 + (nt & 7);
}

// ---------------------------------------------------------------------------
// MFMA GEMM on packed operands. C[M,N] = A[M,K] @ B[N,K]^T.
//
// R11: 128x64 PER WAVE, waves 2x2 (wr = M-strip, wc = N-half); block =
// 256x128. R10's 128x128/wave needed ~384 regs -> allocator capped at 256
// and spilled (FETCH 185MB->2.34GB, WRITE 65MB->4.45GB, 1950us). Lesson:
// usable per-wave budget is <=256. This config: acc 8x4 f32x4 = 128 +
// A-pingpong 64 + B-pingpong 32 + addressing ~= 250 <= 256, no spill.
// Traffic: 4 waves x 12 frags x 1KB = 48KB/kt per 32K outputs = 1.5 B/out/kt
// vs R5's 2.0 (0.75x). (R10 side-result: HBM sustained 3.57 TB/s during the
// spill -- R5's 830 GB/s was nowhere near an HBM limit.) Same fragment math
// and accumulation order -> bit-identical output.
//
// XCD swizzle: L%8 ~ XCD; XCD owns contiguous m-strips (gridDim.y=64, %8=0).
// MODE 0: out bf16 row-major = acc + bias   (-> XP)
// MODE 1: gate: XCp <- sigmoid(acc+bias) * (H@C^T + Dp*XCp), packed in-place
// MODE 2: out fp32 row-major = acc + bias   (-> final out)
// ---------------------------------------------------------------------------
template <int MODE>
__global__ __launch_bounds__(256, 1)
void mfma_gemm(const u16* __restrict__ Ag, const u16* __restrict__ Bg,
               int K, int Nst,
               const float* __restrict__ bias,
               u16* __restrict__ outb, float* __restrict__ outf,
               const float* __restrict__ Hm, const float* __restrict__ Cm,
               const float* __restrict__ Dp, u16* __restrict__ XCp)
{
    const int t     = threadIdx.x;
    const int lane  = t & 63;
    const int w     = t >> 6;
    const int wr    = w & 1;        // M strip (0/1) within block
    const int wc    = w >> 1;       // N half (0/1) within block
    const int col_l = lane & 15;
    const int quad  = lane >> 4;

    // XCD-aware swizzle (block->XCD ~ L%8): XCD owns contiguous m-strips.
    const int L = blockIdx.y * gridDim.x + blockIdx.x;
    const int xcd = L & 7, g = L >> 3;
    const int ntile  = g % gridDim.x;
    const int mtileB = xcd * (gridDim.y >> 3) + g / gridDim.x;  // 256-row strip
    const int bmB = mtileB * 256;
    const int bn  = ntile * 128;

    const int KT = K >> 6;
    // wave's A packed tile (Mt = mtileB*2 + wr); B tile shared, wave reads
    // its 64-col half (nsub = wc*4 + j).
    const u16* aw = Ag + ((size_t)(mtileB * 2 + wr) * KT) * 8192 + (size_t)lane * 8;
    const u16* bw = Bg + (size_t)ntile * KT * 8192 + (size_t)(wc * 4 * 2 * 512)
                       + (size_t)lane * 8;

    f32x4 acc[8][4] = {};   // 128x64 per wave: 32 16x16 frags

    auto ldf = [&](short8* da, short8* db, size_t off, int step) {
#pragma unroll
        for (int i = 0; i < 8; ++i)
            da[i] = *(const short8*)(aw + off + (size_t)((i * 2 + step) * 512));
#pragma unroll
        for (int j = 0; j < 4; ++j)
            db[j] = *(const short8*)(bw + off + (size_t)((j * 2 + step) * 512));
    };
    auto mm = [&](short8* a8, short8* b4) {
#pragma unroll
        for (int i = 0; i < 8; ++i)
#pragma unroll
            for (int j = 0; j < 4; ++j)
                acc[i][j] = __builtin_amdgcn_mfma_f32_16x16x32_bf16(
                    a8[i], b4[j], acc[i][j], 0, 0, 0);
    };

    // depth-1 register ping-pong: 32 MFMA (~155cy) between refill and reuse
    short8 A0[8], B0[4], A1[8], B1[4];
    ldf(A0, B0, 0, 0);
    ldf(A1, B1, 0, 1);
    size_t off = 0;
    for (int kt = 0; kt < KT; ++kt) {
        const bool p = kt + 1 < KT;
        mm(A0, B0); if (p) ldf(A0, B0, off + 8192, 0);
        mm(A1, B1); if (p) ldf(A1, B1, off + 8192, 1);
        off += 8192;
    }

    // C/D layout: col = lane&15, row = quad*4 + reg   [verified m89/m91]
    if (MODE == 0) {
#pragma unroll
        for (int j = 0; j < 4; ++j) {
            int n = bn + wc * 64 + j * 16 + col_l;
            float bv = bias[n];
#pragma unroll
            for (int i = 0; i < 8; ++i) {
                int mb = bmB + wr * 128 + i * 16 + quad * 4;
#pragma unroll
                for (int p = 0; p < 4; ++p)
                    outb[(size_t)(mb + p) * Nst + n] = f2bf(acc[i][j][p] + bv);
            }
        }
    } else if (MODE == 1) {
        __shared__ float Hs[256 * HC_STR];   // 17.4 KB
        __shared__ float Cs[128 * HC_STR];   //  8.7 KB
        for (int idx = t; idx < 256 * D_STATE; idx += 256)
            Hs[(idx >> 4) * HC_STR + (idx & 15)] =
                Hm[((size_t)bmB + (idx >> 4)) * D_STATE + (idx & 15)];
        for (int idx = t; idx < 128 * D_STATE; idx += 256)
            Cs[(idx >> 4) * HC_STR + (idx & 15)] =
                Cm[((size_t)(bn + (idx >> 4))) * D_STATE + (idx & 15)];
        __syncthreads();
#pragma unroll
        for (int i = 0; i < 8; ++i) {
            int mlp = wr * 128 + i * 16 + quad * 4;   // local row in block
#pragma unroll
            for (int p = 0; p < 4; ++p) {
                int row = mlp + p;
                float hrow[D_STATE];
#pragma unroll
                for (int s = 0; s < D_STATE; ++s)
                    hrow[s] = Hs[row * HC_STR + s];
#pragma unroll
                for (int j = 0; j < 4; ++j) {
                    int nl = wc * 64 + j * 16 + col_l;
                    int n = bn + nl;
                    float z = acc[i][j][p] + bias[n];
                    float sig = 1.f / (1.f + __expf(-z));
                    float dot = 0.f;
#pragma unroll
                    for (int s = 0; s < D_STATE; ++s)
                        dot += hrow[s] * Cs[nl * HC_STR + s];
                    // packed in-place RMW: read & write the SAME address
                    size_t offx = xcp_off(bmB + row, n);
                    float xc = bf2f(XCp[offx]);
                    XCp[offx] = f2bf(sig * (dot + Dp[n] * xc));
                }
            }
        }
    } else {
#pragma unroll
        for (int j = 0; j < 4; ++j) {
            int n = bn + wc * 64 + j * 16 + col_l;
            float bv = bias[n];
#pragma unroll
            for (int i = 0; i < 8; ++i) {
                int mb = bmB + wr * 128 + i * 16 + quad * 4;
#pragma unroll
                for (int p = 0; p < 4; ++p)
                    outf[(size_t)(mb + p) * Nst + n] = acc[i][j][p] + bv;
            }
        }
    }
}

// ---------------------------------------------------------------------------
// pack x fp32 [16384,1024] -> packed bf16 tiles (K-dim 1024, 16 k-tiles)
// ---------------------------------------------------------------------------
__global__ __launch_bounds__(256)
void pack_x_kernel(const float* __restrict__ x, u16* __restrict__ xp)
{
    const int Kt = blockIdx.x;   // 0..15
    const int Mt = blockIdx.y;   // 0..127
    const int t  = threadIdx.x;
    u16* dst = xp + ((size_t)Mt * 16 + Kt) * 8192;
#pragma unroll
    for (int i = 0; i < 4; ++i) {
        int c   = i * 256 + t;
        int ell = c & 63;
        int row = Mt * 128 + (c >> 7) * 16 + (ell & 15);
        int col = Kt * 64 + (((c >> 6) & 1) * 4 + (ell >> 4)) * 8;
        const float4* src = (const float4*)&x[(size_t)row * D_MODEL + col];
        float4 a = src[0], b = src[1];
        alignas(16) u16 o[8] = {f2bf(a.x), f2bf(a.y), f2bf(a.z), f2bf(a.w),
                                f2bf(b.x), f2bf(b.y), f2bf(b.z), f2bf(b.w)};
        *(short8*)(dst + c * 8) = *(const short8*)o;
    }
}

// ---------------------------------------------------------------------------
// pack W^T: src W [K, Wstride] fp32 (cols colOff..colOff+Nt*128) -> packed
// bf16 tiles of B = W^T [N, K].
// ---------------------------------------------------------------------------
__global__ __launch_bounds__(256)
void pack_w_kernel(const float* __restrict__ W, u16* __restrict__ out,
                   int Wstride, int colOff, int KT)
{
    const int Kt = blockIdx.x;
    const int Nt = blockIdx.y;
    const int t  = threadIdx.x;
    u16* dst = out + ((size_t)Nt * KT + Kt) * 8192;
#pragma unroll
    for (int i = 0; i < 4; ++i) {
        int c    = i * 256 + t;
        int ell  = c & 63;
        int nrow = Nt * 128 + (c >> 7) * 16 + (ell & 15);
        int kcol = Kt * 64 + (((c >> 6) & 1) * 4 + (ell >> 4)) * 8;
        alignas(16) u16 o[8];
#pragma unroll
        for (int q = 0; q < 8; ++q)
            o[q] = f2bf(W[(size_t)(kcol + q) * Wstride + colOff + nrow]);
        *(short8*)(dst + c * 8) = *(const short8*)o;
    }
}

// ---------------------------------------------------------------------------
// causal depthwise conv (taps=4): XP row-major bf16 -> XCp PACKED bf16.
// block per (k-tile, m-tile); writes are fully linear per tile.
// ---------------------------------------------------------------------------
__global__ __launch_bounds__(256)
void conv_kernel(const u16* __restrict__ XP, const float* __restrict__ conv_w,
                 const float* __restrict__ conv_b, u16* __restrict__ XCp)
{
    const int Kt = blockIdx.x;   // 0..31
    const int Mt = blockIdx.y;   // 0..127
    const int t  = threadIdx.x;
    u16* dst = XCp + ((size_t)Mt * 32 + Kt) * 8192;
#pragma unroll
    for (int i = 0; i < 4; ++i) {
        int c   = i * 256 + t;
        int ell = c & 63;
        int mr  = (c >> 7) * 16 + (ell & 15);
        int e   = Kt * 64 + (((c >> 6) & 1) * 4 + (ell >> 4)) * 8;
        int m   = Mt * 128 + mr;
        int l   = m & (SEQ - 1);
        float acc[8];
        {
            float4 c0 = *(const float4*)&conv_b[e];
            float4 c1 = *(const float4*)&conv_b[e + 4];
            acc[0] = c0.x; acc[1] = c0.y; acc[2] = c0.z; acc[3] = c0.w;
            acc[4] = c1.x; acc[5] = c1.y; acc[6] = c1.z; acc[7] = c1.w;
        }
#pragma unroll
        for (int k = 0; k < 4; ++k) {
            if (l - 3 + k >= 0) {
                const short8 xv = *(const short8*)&XP[(size_t)(m - 3 + k) * E_DIM + e];
#pragma unroll
                for (int j = 0; j < 8; ++j)
                    acc[j] += bf2f((u16)xv[j]) * conv_w[(size_t)(e + j) * 4 + k];
            }
        }
        alignas(16) u16 o[8];
#pragma unroll
        for (int j = 0; j < 8; ++j) o[j] = f2bf(acc[j]);
        *(short8*)(dst + c * 8) = *(const short8*)o;
    }
}

// ---------------------------------------------------------------------------
// R5: U partials. block per (Kt-pair kp, Mt); thread t owns row rr=t>>1,
// col-half z=t&1, reads the 8 CONTIGUOUS chunks of its row in each packed
// tile (wave = 4x256 B contiguous segments per q-step -> full line
// utilization). Pair-reduce via one shfl_xor(1); partials Up[kp][m][s]
// summed by u_reduce_kernel. Deterministic; no LDS.
// ---------------------------------------------------------------------------
__global__ __launch_bounds__(256)
void u_part_kernel(const u16* __restrict__ XCp, const float* __restrict__ Amat,
                   float* __restrict__ Up)
{
    const int kp = blockIdx.x;   // 0..15 (K-tile pair)
    const int Mt = blockIdx.y;   // 0..127
    const int t  = threadIdx.x;
    const int rr = t >> 1;       // row within tile, 0..127
    const int z  = t & 1;        // col-half (step)
    const int msub = rr >> 4, r = rr & 15;

    float acc[16];
#pragma unroll
    for (int s = 0; s < 16; ++s) acc[s] = 0.f;

#pragma unroll
    for (int kk = 0; kk < 2; ++kk) {
        const int Kt = kp * 2 + kk;
        const u16* tile = XCp + ((size_t)Mt * 32 + Kt) * 8192;
#pragma unroll
        for (int q = 0; q < 4; ++q) {
            const int c = msub * 128 + z * 64 + q * 16 + r;
            const short8 xv = *(const short8*)(tile + (size_t)c * 8);
            const int e0 = Kt * 64 + (z * 4 + q) * 8;
#pragma unroll
            for (int j = 0; j < 8; ++j) {
                float xq = bf2f((u16)xv[j]);
                const float4* ar = (const float4*)&Amat[(size_t)(e0 + j) * D_STATE];
#pragma unroll
                for (int s4 = 0; s4 < 4; ++s4) {
                    float4 a = ar[s4];
                    acc[s4 * 4 + 0] += xq * a.x; acc[s4 * 4 + 1] += xq * a.y;
                    acc[s4 * 4 + 2] += xq * a.z; acc[s4 * 4 + 3] += xq * a.w;
                }
            }
        }
    }
    // combine the two col-halves (partner lane = t^1, same row)
#pragma unroll
    for (int s = 0; s < 16; ++s) acc[s] += __shfl_xor(acc[s], 1);

    if (z == 0) {
        const int m = Mt * 128 + rr;
        float4* dst = (float4*)&Up[((size_t)kp * M_ROWS + m) * D_STATE];
        dst[0] = make_float4(acc[0], acc[1], acc[2], acc[3]);
        dst[1] = make_float4(acc[4], acc[5], acc[6], acc[7]);
        dst[2] = make_float4(acc[8], acc[9], acc[10], acc[11]);
        dst[3] = make_float4(acc[12], acc[13], acc[14], acc[15]);
    }
}

// U[m,s] = sum_kp Up[kp][m][s]   (16 coalesced slices, float4-vectorized)
__global__ __launch_bounds__(256)
void u_reduce_kernel(const float* __restrict__ Up, float* __restrict__ U)
{
    const int idx = blockIdx.x * 256 + threadIdx.x;   // 65536 float4 elems
    const float4* src = (const float4*)Up;
    float4 s = src[idx];
#pragma unroll
    for (int kp = 1; kp < 16; ++kp) {
        float4 v = src[(size_t)kp * (M_ROWS * D_STATE / 4) + idx];
        s.x += v.x; s.y += v.y; s.z += v.z; s.w += v.w;
    }
    ((float4*)U)[idx] = s;
}

// ---------------------------------------------------------------------------
// sequential scan: h_l = tanh(U_l + h_{l-1}), 64 chains.
// Chunked by 8 with FULLY-UNROLLED static-index arrays (stay in VGPRs).
// ---------------------------------------------------------------------------
__global__ __launch_bounds__(64)
void scan_kernel(const float* __restrict__ U, float* __restrict__ H)
{
    const int t = threadIdx.x;
    const int b = t >> 4;
    const int s = t & 15;
    const float* u = U + (size_t)b * SEQ * D_STATE + s;
    float*       h = H + (size_t)b * SEQ * D_STATE + s;

    float cur[8], nxt[8];
#pragma unroll
    for (int j = 0; j < 8; ++j) cur[j] = u[(size_t)j * D_STATE];

    float hv = 0.f;
    for (int l0 = 0; l0 < SEQ; l0 += 8) {
        if (l0 + 8 < SEQ) {
#pragma unroll
            for (int j = 0; j < 8; ++j)
                nxt[j] = u[(size_t)(l0 + 8 + j) * D_STATE];
        }
#pragma unroll
        for (int j = 0; j < 8; ++j) {
            float ex = __expf(2.f * (cur[j] + hv));
            hv = 1.f - 2.f / (ex + 1.f);
            h[(size_t)(l0 + j) * D_STATE] = hv;
        }
#pragma unroll
        for (int j = 0; j < 8; ++j) cur[j] = nxt[j];
    }
}

// ---------------------------------------------------------------------------
extern "C" void kernel_launch(void* const* d_in, const int* in_sizes, int n_in,
                              void* d_out, int out_size, void* d_ws, size_t ws_size,
                              hipStream_t stream)
{
    const float* x      = (const float*)d_in[0];
    const float* W_in   = (const float*)d_in[1];
    const float* b_in   = (const float*)d_in[2];
    const float* conv_w = (const float*)d_in[3];
    const float* conv_b = (const float*)d_in[4];
    const float* Amat   = (const float*)d_in[5];
    const float* Cmat   = (const float*)d_in[6];
    const float* Dp     = (const float*)d_in[7];
    const float* W_out  = (const float*)d_in[8];
    const float* b_out  = (const float*)d_in[9];
    float* out = (float*)d_out;

    // workspace layout (132.1 MB total; 136 MB proven safe)
    char* ws = (char*)d_ws;
    u16*   xbp  = (u16*)(ws);                    // 33.55 MB packed x
    u16*   Wp0  = (u16*)(ws +  33554432);        //  4.19 MB packed W_in[:, :2048]^T
    u16*   Wp1  = (u16*)(ws +  37748736);        //  4.19 MB packed W_in[:, 2048:]^T
    u16*   Wp2  = (u16*)(ws +  41943040);        //  4.19 MB packed W_out^T
    u16*   XCp  = (u16*)(ws +  46137344);        // 67.11 MB packed x_conv
    float* U    = (float*)(ws + 113246208);      //  1.05 MB
    float* H    = (float*)(ws + 114294784);      //  1.05 MB
    float* Up   = (float*)(ws + 115343360);      // 16.78 MB U partials (16x)
    u16*   XP   = (u16*)d_out;  // x_proj bf16 in d_out (67.1 MB), dead after conv

    // 1) pack inputs
    pack_x_kernel<<<dim3(16, 128), 256, 0, stream>>>(x, xbp);
    pack_w_kernel<<<dim3(16, 16), 256, 0, stream>>>(W_in, Wp0, 2 * E_DIM, 0, 16);
    pack_w_kernel<<<dim3(16, 16), 256, 0, stream>>>(W_in, Wp1, 2 * E_DIM, E_DIM, 16);
    pack_w_kernel<<<dim3(32, 8), 256, 0, stream>>>(W_out, Wp2, D_MODEL, 0, 32);

    // 2) XP = bf16(x @ W_in[:, :2048] + b_in)   (row-major, -> d_out)
    mfma_gemm<0><<<dim3(16, 64), 256, 0, stream>>>(
        xbp, Wp0, D_MODEL, E_DIM, b_in, XP, nullptr, nullptr, nullptr, nullptr, nullptr);

    // 3) XCp = packed bf16(causal_conv(XP) + conv_b)
    conv_kernel<<<dim3(32, 128), 256, 0, stream>>>(XP, conv_w, conv_b, XCp);

    // 4) U = XC @ A  (partials + reduce); 5) scan -> H
    u_part_kernel<<<dim3(16, 128), 256, 0, stream>>>(XCp, Amat, Up);
    u_reduce_kernel<<<256, 256, 0, stream>>>(Up, U);
    scan_kernel<<<1, 64, 0, stream>>>(U, H);

    // 6) XCp <- sigmoid(x @ W_in[:, 2048:] + b_in[2048:]) * (H@C^T + Dp*XCp)
    mfma_gemm<1><<<dim3(16, 64), 256, 0, stream>>>(
        xbp, Wp1, D_MODEL, 0, b_in + E_DIM, nullptr, nullptr, H, Cmat, Dp, XCp);

    // 7) out = XC @ W_out + b_out   (fp32, row-major)
    mfma_gemm<2><<<dim3(8, 64), 256, 0, stream>>>(
        XCp, Wp2, E_DIM, D_MODEL, b_out, nullptr, out, nullptr, nullptr, nullptr, nullptr);
}

// Round 13
// 1030.665 us; speedup vs baseline: 2.6712x; 1.2501x over previous
//
#include <hip/hip_runtime.h>
#include <cstdint>
#include <cstddef>

#define D_MODEL 1024
#define D_STATE 16
#define E_DIM   2048
#define SEQ     4096
#define M_ROWS  16384

typedef unsigned short u16;
typedef unsigned int   u32;
typedef __attribute__((ext_vector_type(8))) short short8;   // 8 bf16 = 4 VGPRs
typedef __attribute__((ext_vector_type(4))) float f32x4;

__device__ __forceinline__ u16 f2bf(float f) {
    u32 u = __float_as_uint(f);
    u32 r = (u + 0x7fffu + ((u >> 16) & 1u)) >> 16;   // RNE
    return (u16)r;
}
__device__ __forceinline__ float bf2f(u16 h) {
    return __uint_as_float(((u32)h) << 16);
}

// async global->LDS, 16 B per lane. LDS dest is wave-uniform base + lane*16.
__device__ __forceinline__ void gld_lds16(const void* g, void* l) {
    __builtin_amdgcn_global_load_lds(
        (__attribute__((address_space(1))) void*)(uintptr_t)g,
        (__attribute__((address_space(3))) void*)(uintptr_t)l,
        16, 0, 0);
}

// ---------------------------------------------------------------------------
// PACKED TILE LAYOUT: every GEMM operand is stored as fragment-linear 128x64
// bf16 tiles (8192 u16). Chunk c (0..1023, 16 B each): msub=c>>7,
// step=(c>>6)&1, ell=c&63 -> row = msub*16+(ell&15),
// cols = (step*4 + (ell>>4))*8 .. +7.  A lane's MFMA fragment (sub, step) is
// the 16 contiguous bytes at tile_base + ((sub*2+step)*64 + lane)*8 u16.
// Tile (Mt, Kt) of an [M, K] operand lives at ((Mt*(K/64) + Kt) * 8192).
// ---------------------------------------------------------------------------
#define HC_STR 17   // padded float stride for epilogue H/C tiles

// packed elementwise offset for XCp (K-dim = E_DIM = 2048, 32 k-tiles)
__device__ __forceinline__ size_t xcp_off(int m, int n) {
    int Mt = m >> 7, mr = m & 127;
    int Kt = n >> 6, nt = n & 63;
    int c16 = nt >> 3;
    int c = (mr >> 4) * 128 + (c16 >> 2) * 64 + (c16 & 3) * 16 + (mr & 15);
    return ((size_t)Mt * 32 + Kt) * 8192 + (size_t)c * 8 + (nt & 7);
}

union __align__(16) SMem {
    // 2 staging buffers x {2 A-tiles, 2 B-tiles} x 16KB = 128 KB
    struct { u16 A[2][2][8192]; u16 B[2][2][8192]; } s;
    struct { float H[256 * HC_STR]; float C[256 * HC_STR]; } e;  // 17.4K x2
};

// ---------------------------------------------------------------------------
// MFMA GEMM on packed operands. C[M,N] = A[M,K] @ B[N,K]^T.
//
// R13: m201-LITE LDS PIPELINE. R5/R7/R8 reg-direct all saturate the per-CU
// vector-memory path at ~10.5 B/cy (R5 model: 8MB/CU / 10.5 B/cy = 317us vs
// 308 measured -- closes to 3%); duplicated per-wave fragment reads are the
// bytes. LDS staging moves each byte ONCE via global_load_lds (DMA), then
// fragments ride the separate DS pipe (~3x BW). R0-R3's LDS failures were
// drain-0 barriers, not the concept (T4: counted vmcnt is the lever).
// Structure: 256x256 tile, 512 thr (8 waves = 2Mx4N, 2 waves/SIMD), BK=64,
// 2 LDS buffers; stage(kt) = 8 gload_lds/wave. Steady loop (NO drains):
//   iter j: { vmcnt(8)  [stage(j) retired, stage(j+1) stays in flight]
//             s_barrier; compute buf[j&1]; s_barrier;
//             stage(j+2) -> buf[j&1] }
// Only the final iteration uses vmcnt(0). Staged bytes 537MB/GEMM (1.0
// B/out/kt vs reg-direct 2.0). Same accumulation order -> bit-identical.
//
// XCD swizzle: L%8 ~ XCD; XCD owns contiguous m-strips (gridDim.y=64, %8=0).
// MODE 0: out bf16 row-major = acc + bias   (-> XP)
// MODE 1: gate: XCp <- sigmoid(acc+bias) * (H@C^T + Dp*XCp), packed in-place
// MODE 2: out fp32 row-major = acc + bias   (-> final out)
// ---------------------------------------------------------------------------
template <int MODE>
__global__ __launch_bounds__(512, 2)
void mfma_gemm(const u16* __restrict__ Ag, const u16* __restrict__ Bg,
               int K, int Nst,
               const float* __restrict__ bias,
               u16* __restrict__ outb, float* __restrict__ outf,
               const float* __restrict__ Hm, const float* __restrict__ Cm,
               const float* __restrict__ Dp, u16* __restrict__ XCp)
{
    __shared__ SMem sm;
    const int t     = threadIdx.x;
    const int lane  = t & 63;
    const int w     = t >> 6;       // 0..7
    const int wr    = w >> 2;       // M strip (0/1): 128 rows
    const int wc    = w & 3;        // N strip (0..3): 64 cols
    const int col_l = lane & 15;
    const int quad  = lane >> 4;

    // XCD-aware swizzle (block->XCD ~ L%8): XCD owns contiguous m-strips.
    const int L = blockIdx.y * gridDim.x + blockIdx.x;
    const int xcd = L & 7, g = L >> 3;
    const int ntile  = g % gridDim.x;
    const int mtileB = xcd * (gridDim.y >> 3) + g / gridDim.x;  // 256-row strip
    const int bmB = mtileB * 256;
    const int bn  = ntile * 256;

    const int KT = K >> 6;
    const u16* Ab[2] = { Ag + (size_t)(mtileB * 2 + 0) * KT * 8192,
                         Ag + (size_t)(mtileB * 2 + 1) * KT * 8192 };
    const u16* Bb[2] = { Bg + (size_t)(ntile * 2 + 0) * KT * 8192,
                         Bg + (size_t)(ntile * 2 + 1) * KT * 8192 };

    f32x4 acc[8][4] = {};   // 128x64 per wave: 32 16x16 frags

    // stage k-tile j into buffer buf: 8 gload_lds per thread (4 A + 4 B)
    auto stage = [&](int j, int buf) {
        const size_t ko = (size_t)j * 8192;
#pragma unroll
        for (int h = 0; h < 2; ++h) {
#pragma unroll
            for (int q = 0; q < 2; ++q) {
                const int c = q * 512 + t;   // chunk 0..1023 (16 B each)
                gld_lds16(Ab[h] + ko + (size_t)c * 8, &sm.s.A[buf][h][c * 8]);
            }
        }
#pragma unroll
        for (int h = 0; h < 2; ++h) {
#pragma unroll
            for (int q = 0; q < 2; ++q) {
                const int c = q * 512 + t;
                gld_lds16(Bb[h] + ko + (size_t)c * 8, &sm.s.B[buf][h][c * 8]);
            }
        }
    };

    auto compute = [&](int buf) {
#pragma unroll
        for (int step = 0; step < 2; ++step) {
            short8 af[8], bfr[4];
#pragma unroll
            for (int i = 0; i < 8; ++i)
                af[i] = *(const short8*)&sm.s.A[buf][wr][((i * 2 + step) * 64 + lane) * 8];
#pragma unroll
            for (int j = 0; j < 4; ++j) {
                int nsub = wc * 4 + j;            // 0..15 over 256 cols
                int hb = nsub >> 3, ms = nsub & 7;
                bfr[j] = *(const short8*)&sm.s.B[buf][hb][((ms * 2 + step) * 64 + lane) * 8];
            }
#pragma unroll
            for (int i = 0; i < 8; ++i)
#pragma unroll
                for (int j = 0; j < 4; ++j)
                    acc[i][j] = __builtin_amdgcn_mfma_f32_16x16x32_bf16(
                        af[i], bfr[j], acc[i][j], 0, 0, 0);
        }
    };

    // prologue: fill both buffers
    stage(0, 0);
    if (KT > 1) stage(1, 1);

    for (int j = 0; j < KT; ++j) {
        if (j + 1 < KT) {
            asm volatile("s_waitcnt vmcnt(8)" ::: "memory");   // stage(j) done
        } else {
            asm volatile("s_waitcnt vmcnt(0)" ::: "memory");   // final drain
        }
        __builtin_amdgcn_sched_barrier(0);
        __builtin_amdgcn_s_barrier();      // buf[j&1] ready for all waves
        compute(j & 1);
        __builtin_amdgcn_s_barrier();      // all waves done reading buf[j&1]
        if (j + 2 < KT) stage(j + 2, j & 1);
    }

    // C/D layout: col = lane&15, row = quad*4 + reg   [verified m89/m91]
    if (MODE == 0) {
#pragma unroll
        for (int j = 0; j < 4; ++j) {
            int n = bn + wc * 64 + j * 16 + col_l;
            float bv = bias[n];
#pragma unroll
            for (int i = 0; i < 8; ++i) {
                int mb = bmB + wr * 128 + i * 16 + quad * 4;
#pragma unroll
                for (int p = 0; p < 4; ++p)
                    outb[(size_t)(mb + p) * Nst + n] = f2bf(acc[i][j][p] + bv);
            }
        }
    } else if (MODE == 1) {
        __syncthreads();   // staging LDS dead; reuse union for H/C tiles
        for (int idx = t; idx < 256 * D_STATE; idx += 512)
            sm.e.H[(idx >> 4) * HC_STR + (idx & 15)] =
                Hm[((size_t)bmB + (idx >> 4)) * D_STATE + (idx & 15)];
        for (int idx = t; idx < 256 * D_STATE; idx += 512)
            sm.e.C[(idx >> 4) * HC_STR + (idx & 15)] =
                Cm[((size_t)(bn + (idx >> 4))) * D_STATE + (idx & 15)];
        __syncthreads();
#pragma unroll
        for (int i = 0; i < 8; ++i) {
            int mlp = wr * 128 + i * 16 + quad * 4;   // local row in block
#pragma unroll
            for (int p = 0; p < 4; ++p) {
                int row = mlp + p;
                float hrow[D_STATE];
#pragma unroll
                for (int s = 0; s < D_STATE; ++s)
                    hrow[s] = sm.e.H[row * HC_STR + s];
#pragma unroll
                for (int j = 0; j < 4; ++j) {
                    int nl = wc * 64 + j * 16 + col_l;
                    int n = bn + nl;
                    float z = acc[i][j][p] + bias[n];
                    float sig = 1.f / (1.f + __expf(-z));
                    float dot = 0.f;
#pragma unroll
                    for (int s = 0; s < D_STATE; ++s)
                        dot += hrow[s] * sm.e.C[nl * HC_STR + s];
                    // packed in-place RMW: read & write the SAME address
                    size_t offx = xcp_off(bmB + row, n);
                    float xc = bf2f(XCp[offx]);
                    XCp[offx] = f2bf(sig * (dot + Dp[n] * xc));
                }
            }
        }
    } else {
#pragma unroll
        for (int j = 0; j < 4; ++j) {
            int n = bn + wc * 64 + j * 16 + col_l;
            float bv = bias[n];
#pragma unroll
            for (int i = 0; i < 8; ++i) {
                int mb = bmB + wr * 128 + i * 16 + quad * 4;
#pragma unroll
                for (int p = 0; p < 4; ++p)
                    outf[(size_t)(mb + p) * Nst + n] = acc[i][j][p] + bv;
            }
        }
    }
}

// ---------------------------------------------------------------------------
// pack x fp32 [16384,1024] -> packed bf16 tiles (K-dim 1024, 16 k-tiles)
// ---------------------------------------------------------------------------
__global__ __launch_bounds__(256)
void pack_x_kernel(const float* __restrict__ x, u16* __restrict__ xp)
{
    const int Kt = blockIdx.x;   // 0..15
    const int Mt = blockIdx.y;   // 0..127
    const int t  = threadIdx.x;
    u16* dst = xp + ((size_t)Mt * 16 + Kt) * 8192;
#pragma unroll
    for (int i = 0; i < 4; ++i) {
        int c   = i * 256 + t;
        int ell = c & 63;
        int row = Mt * 128 + (c >> 7) * 16 + (ell & 15);
        int col = Kt * 64 + (((c >> 6) & 1) * 4 + (ell >> 4)) * 8;
        const float4* src = (const float4*)&x[(size_t)row * D_MODEL + col];
        float4 a = src[0], b = src[1];
        alignas(16) u16 o[8] = {f2bf(a.x), f2bf(a.y), f2bf(a.z), f2bf(a.w),
                                f2bf(b.x), f2bf(b.y), f2bf(b.z), f2bf(b.w)};
        *(short8*)(dst + c * 8) = *(const short8*)o;
    }
}

// ---------------------------------------------------------------------------
// pack W^T: src W [K, Wstride] fp32 (cols colOff..colOff+Nt*128) -> packed
// bf16 tiles of B = W^T [N, K].
// ---------------------------------------------------------------------------
__global__ __launch_bounds__(256)
void pack_w_kernel(const float* __restrict__ W, u16* __restrict__ out,
                   int Wstride, int colOff, int KT)
{
    const int Kt = blockIdx.x;
    const int Nt = blockIdx.y;
    const int t  = threadIdx.x;
    u16* dst = out + ((size_t)Nt * KT + Kt) * 8192;
#pragma unroll
    for (int i = 0; i < 4; ++i) {
        int c    = i * 256 + t;
        int ell  = c & 63;
        int nrow = Nt * 128 + (c >> 7) * 16 + (ell & 15);
        int kcol = Kt * 64 + (((c >> 6) & 1) * 4 + (ell >> 4)) * 8;
        alignas(16) u16 o[8];
#pragma unroll
        for (int q = 0; q < 8; ++q)
            o[q] = f2bf(W[(size_t)(kcol + q) * Wstride + colOff + nrow]);
        *(short8*)(dst + c * 8) = *(const short8*)o;
    }
}

// ---------------------------------------------------------------------------
// causal depthwise conv (taps=4): XP row-major bf16 -> XCp PACKED bf16.
// block per (k-tile, m-tile); writes are fully linear per tile.
// ---------------------------------------------------------------------------
__global__ __launch_bounds__(256)
void conv_kernel(const u16* __restrict__ XP, const float* __restrict__ conv_w,
                 const float* __restrict__ conv_b, u16* __restrict__ XCp)
{
    const int Kt = blockIdx.x;   // 0..31
    const int Mt = blockIdx.y;   // 0..127
    const int t  = threadIdx.x;
    u16* dst = XCp + ((size_t)Mt * 32 + Kt) * 8192;
#pragma unroll
    for (int i = 0; i < 4; ++i) {
        int c   = i * 256 + t;
        int ell = c & 63;
        int mr  = (c >> 7) * 16 + (ell & 15);
        int e   = Kt * 64 + (((c >> 6) & 1) * 4 + (ell >> 4)) * 8;
        int m   = Mt * 128 + mr;
        int l   = m & (SEQ - 1);
        float acc[8];
        {
            float4 c0 = *(const float4*)&conv_b[e];
            float4 c1 = *(const float4*)&conv_b[e + 4];
            acc[0] = c0.x; acc[1] = c0.y; acc[2] = c0.z; acc[3] = c0.w;
            acc[4] = c1.x; acc[5] = c1.y; acc[6] = c1.z; acc[7] = c1.w;
        }
#pragma unroll
        for (int k = 0; k < 4; ++k) {
            if (l - 3 + k >= 0) {
                const short8 xv = *(const short8*)&XP[(size_t)(m - 3 + k) * E_DIM + e];
#pragma unroll
                for (int j = 0; j < 8; ++j)
                    acc[j] += bf2f((u16)xv[j]) * conv_w[(size_t)(e + j) * 4 + k];
            }
        }
        alignas(16) u16 o[8];
#pragma unroll
        for (int j = 0; j < 8; ++j) o[j] = f2bf(acc[j]);
        *(short8*)(dst + c * 8) = *(const short8*)o;
    }
}

// ---------------------------------------------------------------------------
// R5: U partials. block per (Kt-pair kp, Mt); thread t owns row rr=t>>1,
// col-half z=t&1, reads the 8 CONTIGUOUS chunks of its row in each packed
// tile (wave = 4x256 B contiguous segments per q-step -> full line
// utilization). Pair-reduce via one shfl_xor(1); partials Up[kp][m][s]
// summed by u_reduce_kernel. Deterministic; no LDS.
// ---------------------------------------------------------------------------
__global__ __launch_bounds__(256)
void u_part_kernel(const u16* __restrict__ XCp, const float* __restrict__ Amat,
                   float* __restrict__ Up)
{
    const int kp = blockIdx.x;   // 0..15 (K-tile pair)
    const int Mt = blockIdx.y;   // 0..127
    const int t  = threadIdx.x;
    const int rr = t >> 1;       // row within tile, 0..127
    const int z  = t & 1;        // col-half (step)
    const int msub = rr >> 4, r = rr & 15;

    float acc[16];
#pragma unroll
    for (int s = 0; s < 16; ++s) acc[s] = 0.f;

#pragma unroll
    for (int kk = 0; kk < 2; ++kk) {
        const int Kt = kp * 2 + kk;
        const u16* tile = XCp + ((size_t)Mt * 32 + Kt) * 8192;
#pragma unroll
        for (int q = 0; q < 4; ++q) {
            const int c = msub * 128 + z * 64 + q * 16 + r;
            const short8 xv = *(const short8*)(tile + (size_t)c * 8);
            const int e0 = Kt * 64 + (z * 4 + q) * 8;
#pragma unroll
            for (int j = 0; j < 8; ++j) {
                float xq = bf2f((u16)xv[j]);
                const float4* ar = (const float4*)&Amat[(size_t)(e0 + j) * D_STATE];
#pragma unroll
                for (int s4 = 0; s4 < 4; ++s4) {
                    float4 a = ar[s4];
                    acc[s4 * 4 + 0] += xq * a.x; acc[s4 * 4 + 1] += xq * a.y;
                    acc[s4 * 4 + 2] += xq * a.z; acc[s4 * 4 + 3] += xq * a.w;
                }
            }
        }
    }
    // combine the two col-halves (partner lane = t^1, same row)
#pragma unroll
    for (int s = 0; s < 16; ++s) acc[s] += __shfl_xor(acc[s], 1);

    if (z == 0) {
        const int m = Mt * 128 + rr;
        float4* dst = (float4*)&Up[((size_t)kp * M_ROWS + m) * D_STATE];
        dst[0] = make_float4(acc[0], acc[1], acc[2], acc[3]);
        dst[1] = make_float4(acc[4], acc[5], acc[6], acc[7]);
        dst[2] = make_float4(acc[8], acc[9], acc[10], acc[11]);
        dst[3] = make_float4(acc[12], acc[13], acc[14], acc[15]);
    }
}

// U[m,s] = sum_kp Up[kp][m][s]   (16 coalesced slices, float4-vectorized)
__global__ __launch_bounds__(256)
void u_reduce_kernel(const float* __restrict__ Up, float* __restrict__ U)
{
    const int idx = blockIdx.x * 256 + threadIdx.x;   // 65536 float4 elems
    const float4* src = (const float4*)Up;
    float4 s = src[idx];
#pragma unroll
    for (int kp = 1; kp < 16; ++kp) {
        float4 v = src[(size_t)kp * (M_ROWS * D_STATE / 4) + idx];
        s.x += v.x; s.y += v.y; s.z += v.z; s.w += v.w;
    }
    ((float4*)U)[idx] = s;
}

// ---------------------------------------------------------------------------
// sequential scan: h_l = tanh(U_l + h_{l-1}), 64 chains.
// Chunked by 8 with FULLY-UNROLLED static-index arrays (stay in VGPRs).
// ---------------------------------------------------------------------------
__global__ __launch_bounds__(64)
void scan_kernel(const float* __restrict__ U, float* __restrict__ H)
{
    const int t = threadIdx.x;
    const int b = t >> 4;
    const int s = t & 15;
    const float* u = U + (size_t)b * SEQ * D_STATE + s;
    float*       h = H + (size_t)b * SEQ * D_STATE + s;

    float cur[8], nxt[8];
#pragma unroll
    for (int j = 0; j < 8; ++j) cur[j] = u[(size_t)j * D_STATE];

    float hv = 0.f;
    for (int l0 = 0; l0 < SEQ; l0 += 8) {
        if (l0 + 8 < SEQ) {
#pragma unroll
            for (int j = 0; j < 8; ++j)
                nxt[j] = u[(size_t)(l0 + 8 + j) * D_STATE];
        }
#pragma unroll
        for (int j = 0; j < 8; ++j) {
            float ex = __expf(2.f * (cur[j] + hv));
            hv = 1.f - 2.f / (ex + 1.f);
            h[(size_t)(l0 + j) * D_STATE] = hv;
        }
#pragma unroll
        for (int j = 0; j < 8; ++j) cur[j] = nxt[j];
    }
}

// ---------------------------------------------------------------------------
extern "C" void kernel_launch(void* const* d_in, const int* in_sizes, int n_in,
                              void* d_out, int out_size, void* d_ws, size_t ws_size,
                              hipStream_t stream)
{
    const float* x      = (const float*)d_in[0];
    const float* W_in   = (const float*)d_in[1];
    const float* b_in   = (const float*)d_in[2];
    const float* conv_w = (const float*)d_in[3];
    const float* conv_b = (const float*)d_in[4];
    const float* Amat   = (const float*)d_in[5];
    const float* Cmat   = (const float*)d_in[6];
    const float* Dp     = (const float*)d_in[7];
    const float* W_out  = (const float*)d_in[8];
    const float* b_out  = (const float*)d_in[9];
    float* out = (float*)d_out;

    // workspace layout (132.1 MB total; 136 MB proven safe)
    char* ws = (char*)d_ws;
    u16*   xbp  = (u16*)(ws);                    // 33.55 MB packed x
    u16*   Wp0  = (u16*)(ws +  33554432);        //  4.19 MB packed W_in[:, :2048]^T
    u16*   Wp1  = (u16*)(ws +  37748736);        //  4.19 MB packed W_in[:, 2048:]^T
    u16*   Wp2  = (u16*)(ws +  41943040);        //  4.19 MB packed W_out^T
    u16*   XCp  = (u16*)(ws +  46137344);        // 67.11 MB packed x_conv
    float* U    = (float*)(ws + 113246208);      //  1.05 MB
    float* H    = (float*)(ws + 114294784);      //  1.05 MB
    float* Up   = (float*)(ws + 115343360);      // 16.78 MB U partials (16x)
    u16*   XP   = (u16*)d_out;  // x_proj bf16 in d_out (67.1 MB), dead after conv

    // 1) pack inputs
    pack_x_kernel<<<dim3(16, 128), 256, 0, stream>>>(x, xbp);
    pack_w_kernel<<<dim3(16, 16), 256, 0, stream>>>(W_in, Wp0, 2 * E_DIM, 0, 16);
    pack_w_kernel<<<dim3(16, 16), 256, 0, stream>>>(W_in, Wp1, 2 * E_DIM, E_DIM, 16);
    pack_w_kernel<<<dim3(32, 8), 256, 0, stream>>>(W_out, Wp2, D_MODEL, 0, 32);

    // 2) XP = bf16(x @ W_in[:, :2048] + b_in)   (row-major, -> d_out)
    mfma_gemm<0><<<dim3(8, 64), 512, 0, stream>>>(
        xbp, Wp0, D_MODEL, E_DIM, b_in, XP, nullptr, nullptr, nullptr, nullptr, nullptr);

    // 3) XCp = packed bf16(causal_conv(XP) + conv_b)
    conv_kernel<<<dim3(32, 128), 256, 0, stream>>>(XP, conv_w, conv_b, XCp);

    // 4) U = XC @ A  (partials + reduce); 5) scan -> H
    u_part_kernel<<<dim3(16, 128), 256, 0, stream>>>(XCp, Amat, Up);
    u_reduce_kernel<<<256, 256, 0, stream>>>(Up, U);
    scan_kernel<<<1, 64, 0, stream>>>(U, H);

    // 6) XCp <- sigmoid(x @ W_in[:, 2048:] + b_in[2048:]) * (H@C^T + Dp*XCp)
    mfma_gemm<1><<<dim3(8, 64), 512, 0, stream>>>(
        xbp, Wp1, D_MODEL, 0, b_in + E_DIM, nullptr, nullptr, H, Cmat, Dp, XCp);

    // 7) out = XC @ W_out + b_out   (fp32, row-major)
    mfma_gemm<2><<<dim3(4, 64), 512, 0, stream>>>(
        XCp, Wp2, E_DIM, D_MODEL, b_out, nullptr, out, nullptr, nullptr, nullptr, nullptr);
}

// Round 14
// 901.779 us; speedup vs baseline: 3.0530x; 1.1429x over previous
//
#include <hip/hip_runtime.h>
#include <cstdint>
#include <cstddef>

#define D_MODEL 1024
#define D_STATE 16
#define E_DIM   2048
#define SEQ     4096
#define M_ROWS  16384

typedef unsigned short u16;
typedef unsigned int   u32;
typedef __attribute__((ext_vector_type(8))) short short8;   // 8 bf16 = 4 VGPRs
typedef __attribute__((ext_vector_type(4))) float f32x4;

__device__ __forceinline__ u16 f2bf(float f) {
    u32 u = __float_as_uint(f);
    u32 r = (u + 0x7fffu + ((u >> 16) & 1u)) >> 16;   // RNE
    return (u16)r;
}
__device__ __forceinline__ float bf2f(u16 h) {
    return __uint_as_float(((u32)h) << 16);
}

// async global->LDS, 16 B per lane. LDS dest is wave-uniform base + lane*16.
__device__ __forceinline__ void gld_lds16(const void* g, void* l) {
    __builtin_amdgcn_global_load_lds(
        (__attribute__((address_space(1))) void*)(uintptr_t)g,
        (__attribute__((address_space(3))) void*)(uintptr_t)l,
        16, 0, 0);
}

// ---------------------------------------------------------------------------
// PACKED TILE LAYOUT: every GEMM operand is stored as fragment-linear 128x64
// bf16 tiles (8192 u16). Chunk c (0..1023, 16 B each): msub=c>>7,
// step=(c>>6)&1, ell=c&63 -> row = msub*16+(ell&15),
// cols = (step*4 + (ell>>4))*8 .. +7.  A lane's MFMA fragment (sub, step) is
// the 16 contiguous bytes at tile_base + ((sub*2+step)*64 + lane)*8 u16.
// Tile (Mt, Kt) of an [M, K] operand lives at ((Mt*(K/64) + Kt) * 8192).
// ---------------------------------------------------------------------------
#define HC_STR 17   // padded float stride for epilogue H/C tiles

// packed elementwise offset for XCp (K-dim = E_DIM = 2048, 32 k-tiles)
__device__ __forceinline__ size_t xcp_off(int m, int n) {
    int Mt = m >> 7, mr = m & 127;
    int Kt = n >> 6, nt = n & 63;
    int c16 = nt >> 3;
    int c = (mr >> 4) * 128 + (c16 >> 2) * 64 + (c16 & 3) * 16 + (mr & 15);
    return ((size_t)Mt * 32 + Kt) * 8192 + (size_t)c * 8 + (nt & 7);
}

union __align__(16) SMem {
    // 2 staging buffers x {2 A-tiles, 2 B-tiles} x 16KB = 128 KB
    struct { u16 A[2][2][8192]; u16 B[2][2][8192]; } s;
    struct { float H[256 * HC_STR]; float C[256 * HC_STR]; } e;  // 17.4K x2
};

// ---------------------------------------------------------------------------
// MFMA GEMM on packed operands. C[M,N] = A[M,K] @ B[N,K]^T.
//
// R13: m201-LITE LDS PIPELINE (verified R13: steady-state GEMMs dropped out
// of the top-5; only the iteration-0 cold dispatch at 332us remains).
// Reg-direct loops saturate the per-CU vector-memory path at ~10.5 B/cy on
// duplicated per-wave fragment reads; LDS staging moves each byte ONCE via
// global_load_lds (DMA), fragments ride the separate DS pipe.
// Structure: 256x256 tile, 512 thr (8 waves = 2Mx4N, 2 waves/SIMD), BK=64,
// 2 LDS buffers; stage(kt) = 8 gload_lds/wave. Steady loop (NO drains):
//   iter j: { vmcnt(8)  [stage(j) retired, stage(j+1) stays in flight]
//             s_barrier; compute buf[j&1]; s_barrier;
//             stage(j+2) -> buf[j&1] }
// Only the final iteration uses vmcnt(0). Same accumulation order ->
// bit-identical output.
//
// XCD swizzle: L%8 ~ XCD; XCD owns contiguous m-strips (gridDim.y=64, %8=0).
// MODE 0: out bf16 row-major = acc + bias   (-> XP)
// MODE 1: gate: XCp <- sigmoid(acc+bias) * (H@C^T + Dp*XCp), packed in-place
// MODE 2: out fp32 row-major = acc + bias   (-> final out)
// ---------------------------------------------------------------------------
template <int MODE>
__global__ __launch_bounds__(512, 2)
void mfma_gemm(const u16* __restrict__ Ag, const u16* __restrict__ Bg,
               int K, int Nst,
               const float* __restrict__ bias,
               u16* __restrict__ outb, float* __restrict__ outf,
               const float* __restrict__ Hm, const float* __restrict__ Cm,
               const float* __restrict__ Dp, u16* __restrict__ XCp)
{
    __shared__ SMem sm;
    const int t     = threadIdx.x;
    const int lane  = t & 63;
    const int w     = t >> 6;       // 0..7
    const int wr    = w >> 2;       // M strip (0/1): 128 rows
    const int wc    = w & 3;        // N strip (0..3): 64 cols
    const int col_l = lane & 15;
    const int quad  = lane >> 4;

    // XCD-aware swizzle (block->XCD ~ L%8): XCD owns contiguous m-strips.
    const int L = blockIdx.y * gridDim.x + blockIdx.x;
    const int xcd = L & 7, g = L >> 3;
    const int ntile  = g % gridDim.x;
    const int mtileB = xcd * (gridDim.y >> 3) + g / gridDim.x;  // 256-row strip
    const int bmB = mtileB * 256;
    const int bn  = ntile * 256;

    const int KT = K >> 6;
    const u16* Ab[2] = { Ag + (size_t)(mtileB * 2 + 0) * KT * 8192,
                         Ag + (size_t)(mtileB * 2 + 1) * KT * 8192 };
    const u16* Bb[2] = { Bg + (size_t)(ntile * 2 + 0) * KT * 8192,
                         Bg + (size_t)(ntile * 2 + 1) * KT * 8192 };

    f32x4 acc[8][4] = {};   // 128x64 per wave: 32 16x16 frags

    // stage k-tile j into buffer buf: 8 gload_lds per thread (4 A + 4 B)
    auto stage = [&](int j, int buf) {
        const size_t ko = (size_t)j * 8192;
#pragma unroll
        for (int h = 0; h < 2; ++h) {
#pragma unroll
            for (int q = 0; q < 2; ++q) {
                const int c = q * 512 + t;   // chunk 0..1023 (16 B each)
                gld_lds16(Ab[h] + ko + (size_t)c * 8, &sm.s.A[buf][h][c * 8]);
            }
        }
#pragma unroll
        for (int h = 0; h < 2; ++h) {
#pragma unroll
            for (int q = 0; q < 2; ++q) {
                const int c = q * 512 + t;
                gld_lds16(Bb[h] + ko + (size_t)c * 8, &sm.s.B[buf][h][c * 8]);
            }
        }
    };

    auto compute = [&](int buf) {
#pragma unroll
        for (int step = 0; step < 2; ++step) {
            short8 af[8], bfr[4];
#pragma unroll
            for (int i = 0; i < 8; ++i)
                af[i] = *(const short8*)&sm.s.A[buf][wr][((i * 2 + step) * 64 + lane) * 8];
#pragma unroll
            for (int j = 0; j < 4; ++j) {
                int nsub = wc * 4 + j;            // 0..15 over 256 cols
                int hb = nsub >> 3, ms = nsub & 7;
                bfr[j] = *(const short8*)&sm.s.B[buf][hb][((ms * 2 + step) * 64 + lane) * 8];
            }
#pragma unroll
            for (int i = 0; i < 8; ++i)
#pragma unroll
                for (int j = 0; j < 4; ++j)
                    acc[i][j] = __builtin_amdgcn_mfma_f32_16x16x32_bf16(
                        af[i], bfr[j], acc[i][j], 0, 0, 0);
        }
    };

    // prologue: fill both buffers
    stage(0, 0);
    if (KT > 1) stage(1, 1);

    for (int j = 0; j < KT; ++j) {
        if (j + 1 < KT) {
            asm volatile("s_waitcnt vmcnt(8)" ::: "memory");   // stage(j) done
        } else {
            asm volatile("s_waitcnt vmcnt(0)" ::: "memory");   // final drain
        }
        __builtin_amdgcn_sched_barrier(0);
        __builtin_amdgcn_s_barrier();      // buf[j&1] ready for all waves
        compute(j & 1);
        __builtin_amdgcn_s_barrier();      // all waves done reading buf[j&1]
        if (j + 2 < KT) stage(j + 2, j & 1);
    }

    // C/D layout: col = lane&15, row = quad*4 + reg   [verified m89/m91]
    if (MODE == 0) {
#pragma unroll
        for (int j = 0; j < 4; ++j) {
            int n = bn + wc * 64 + j * 16 + col_l;
            float bv = bias[n];
#pragma unroll
            for (int i = 0; i < 8; ++i) {
                int mb = bmB + wr * 128 + i * 16 + quad * 4;
#pragma unroll
                for (int p = 0; p < 4; ++p)
                    outb[(size_t)(mb + p) * Nst + n] = f2bf(acc[i][j][p] + bv);
            }
        }
    } else if (MODE == 1) {
        __syncthreads();   // staging LDS dead; reuse union for H/C tiles
        for (int idx = t; idx < 256 * D_STATE; idx += 512)
            sm.e.H[(idx >> 4) * HC_STR + (idx & 15)] =
                Hm[((size_t)bmB + (idx >> 4)) * D_STATE + (idx & 15)];
        for (int idx = t; idx < 256 * D_STATE; idx += 512)
            sm.e.C[(idx >> 4) * HC_STR + (idx & 15)] =
                Cm[((size_t)(bn + (idx >> 4))) * D_STATE + (idx & 15)];
        __syncthreads();
#pragma unroll
        for (int i = 0; i < 8; ++i) {
            int mlp = wr * 128 + i * 16 + quad * 4;   // local row in block
#pragma unroll
            for (int p = 0; p < 4; ++p) {
                int row = mlp + p;
                float hrow[D_STATE];
#pragma unroll
                for (int s = 0; s < D_STATE; ++s)
                    hrow[s] = sm.e.H[row * HC_STR + s];
#pragma unroll
                for (int j = 0; j < 4; ++j) {
                    int nl = wc * 64 + j * 16 + col_l;
                    int n = bn + nl;
                    float z = acc[i][j][p] + bias[n];
                    float sig = 1.f / (1.f + __expf(-z));
                    float dot = 0.f;
#pragma unroll
                    for (int s = 0; s < D_STATE; ++s)
                        dot += hrow[s] * sm.e.C[nl * HC_STR + s];
                    // packed in-place RMW: read & write the SAME address
                    size_t offx = xcp_off(bmB + row, n);
                    float xc = bf2f(XCp[offx]);
                    XCp[offx] = f2bf(sig * (dot + Dp[n] * xc));
                }
            }
        }
    } else {
#pragma unroll
        for (int j = 0; j < 4; ++j) {
            int n = bn + wc * 64 + j * 16 + col_l;
            float bv = bias[n];
#pragma unroll
            for (int i = 0; i < 8; ++i) {
                int mb = bmB + wr * 128 + i * 16 + quad * 4;
#pragma unroll
                for (int p = 0; p < 4; ++p)
                    outf[(size_t)(mb + p) * Nst + n] = acc[i][j][p] + bv;
            }
        }
    }
}

// ---------------------------------------------------------------------------
// pack x fp32 [16384,1024] -> packed bf16 tiles (K-dim 1024, 16 k-tiles)
// ---------------------------------------------------------------------------
__global__ __launch_bounds__(256)
void pack_x_kernel(const float* __restrict__ x, u16* __restrict__ xp)
{
    const int Kt = blockIdx.x;   // 0..15
    const int Mt = blockIdx.y;   // 0..127
    const int t  = threadIdx.x;
    u16* dst = xp + ((size_t)Mt * 16 + Kt) * 8192;
#pragma unroll
    for (int i = 0; i < 4; ++i) {
        int c   = i * 256 + t;
        int ell = c & 63;
        int row = Mt * 128 + (c >> 7) * 16 + (ell & 15);
        int col = Kt * 64 + (((c >> 6) & 1) * 4 + (ell >> 4)) * 8;
        const float4* src = (const float4*)&x[(size_t)row * D_MODEL + col];
        float4 a = src[0], b = src[1];
        alignas(16) u16 o[8] = {f2bf(a.x), f2bf(a.y), f2bf(a.z), f2bf(a.w),
                                f2bf(b.x), f2bf(b.y), f2bf(b.z), f2bf(b.w)};
        *(short8*)(dst + c * 8) = *(const short8*)o;
    }
}

// ---------------------------------------------------------------------------
// pack W^T: src W [K, Wstride] fp32 (cols colOff..colOff+Nt*128) -> packed
// bf16 tiles of B = W^T [N, K].
// ---------------------------------------------------------------------------
__global__ __launch_bounds__(256)
void pack_w_kernel(const float* __restrict__ W, u16* __restrict__ out,
                   int Wstride, int colOff, int KT)
{
    const int Kt = blockIdx.x;
    const int Nt = blockIdx.y;
    const int t  = threadIdx.x;
    u16* dst = out + ((size_t)Nt * KT + Kt) * 8192;
#pragma unroll
    for (int i = 0; i < 4; ++i) {
        int c    = i * 256 + t;
        int ell  = c & 63;
        int nrow = Nt * 128 + (c >> 7) * 16 + (ell & 15);
        int kcol = Kt * 64 + (((c >> 6) & 1) * 4 + (ell >> 4)) * 8;
        alignas(16) u16 o[8];
#pragma unroll
        for (int q = 0; q < 8; ++q)
            o[q] = f2bf(W[(size_t)(kcol + q) * Wstride + colOff + nrow]);
        *(short8*)(dst + c * 8) = *(const short8*)o;
    }
}

// ---------------------------------------------------------------------------
// causal depthwise conv (taps=4): XP row-major bf16 -> XCp PACKED bf16.
// block per (k-tile, m-tile); writes are fully linear per tile.
// ---------------------------------------------------------------------------
__global__ __launch_bounds__(256)
void conv_kernel(const u16* __restrict__ XP, const float* __restrict__ conv_w,
                 const float* __restrict__ conv_b, u16* __restrict__ XCp)
{
    const int Kt = blockIdx.x;   // 0..31
    const int Mt = blockIdx.y;   // 0..127
    const int t  = threadIdx.x;
    u16* dst = XCp + ((size_t)Mt * 32 + Kt) * 8192;
#pragma unroll
    for (int i = 0; i < 4; ++i) {
        int c   = i * 256 + t;
        int ell = c & 63;
        int mr  = (c >> 7) * 16 + (ell & 15);
        int e   = Kt * 64 + (((c >> 6) & 1) * 4 + (ell >> 4)) * 8;
        int m   = Mt * 128 + mr;
        int l   = m & (SEQ - 1);
        float acc[8];
        {
            float4 c0 = *(const float4*)&conv_b[e];
            float4 c1 = *(const float4*)&conv_b[e + 4];
            acc[0] = c0.x; acc[1] = c0.y; acc[2] = c0.z; acc[3] = c0.w;
            acc[4] = c1.x; acc[5] = c1.y; acc[6] = c1.z; acc[7] = c1.w;
        }
#pragma unroll
        for (int k = 0; k < 4; ++k) {
            if (l - 3 + k >= 0) {
                const short8 xv = *(const short8*)&XP[(size_t)(m - 3 + k) * E_DIM + e];
#pragma unroll
                for (int j = 0; j < 8; ++j)
                    acc[j] += bf2f((u16)xv[j]) * conv_w[(size_t)(e + j) * 4 + k];
            }
        }
        alignas(16) u16 o[8];
#pragma unroll
        for (int j = 0; j < 8; ++j) o[j] = f2bf(acc[j]);
        *(short8*)(dst + c * 8) = *(const short8*)o;
    }
}

// ---------------------------------------------------------------------------
// R5: U partials. block per (Kt-pair kp, Mt); thread t owns row rr=t>>1,
// col-half z=t&1, reads the 8 CONTIGUOUS chunks of its row in each packed
// tile (wave = 4x256 B contiguous segments per q-step -> full line
// utilization). Pair-reduce via one shfl_xor(1); partials Up[kp][m][s]
// summed by u_reduce_kernel. Deterministic; no LDS.
// ---------------------------------------------------------------------------
__global__ __launch_bounds__(256)
void u_part_kernel(const u16* __restrict__ XCp, const float* __restrict__ Amat,
                   float* __restrict__ Up)
{
    const int kp = blockIdx.x;   // 0..15 (K-tile pair)
    const int Mt = blockIdx.y;   // 0..127
    const int t  = threadIdx.x;
    const int rr = t >> 1;       // row within tile, 0..127
    const int z  = t & 1;        // col-half (step)
    const int msub = rr >> 4, r = rr & 15;

    float acc[16];
#pragma unroll
    for (int s = 0; s < 16; ++s) acc[s] = 0.f;

#pragma unroll
    for (int kk = 0; kk < 2; ++kk) {
        const int Kt = kp * 2 + kk;
        const u16* tile = XCp + ((size_t)Mt * 32 + Kt) * 8192;
#pragma unroll
        for (int q = 0; q < 4; ++q) {
            const int c = msub * 128 + z * 64 + q * 16 + r;
            const short8 xv = *(const short8*)(tile + (size_t)c * 8);
            const int e0 = Kt * 64 + (z * 4 + q) * 8;
#pragma unroll
            for (int j = 0; j < 8; ++j) {
                float xq = bf2f((u16)xv[j]);
                const float4* ar = (const float4*)&Amat[(size_t)(e0 + j) * D_STATE];
#pragma unroll
                for (int s4 = 0; s4 < 4; ++s4) {
                    float4 a = ar[s4];
                    acc[s4 * 4 + 0] += xq * a.x; acc[s4 * 4 + 1] += xq * a.y;
                    acc[s4 * 4 + 2] += xq * a.z; acc[s4 * 4 + 3] += xq * a.w;
                }
            }
        }
    }
    // combine the two col-halves (partner lane = t^1, same row)
#pragma unroll
    for (int s = 0; s < 16; ++s) acc[s] += __shfl_xor(acc[s], 1);

    if (z == 0) {
        const int m = Mt * 128 + rr;
        float4* dst = (float4*)&Up[((size_t)kp * M_ROWS + m) * D_STATE];
        dst[0] = make_float4(acc[0], acc[1], acc[2], acc[3]);
        dst[1] = make_float4(acc[4], acc[5], acc[6], acc[7]);
        dst[2] = make_float4(acc[8], acc[9], acc[10], acc[11]);
        dst[3] = make_float4(acc[12], acc[13], acc[14], acc[15]);
    }
}

// U[m,s] = sum_kp Up[kp][m][s]   (16 coalesced slices, float4-vectorized)
__global__ __launch_bounds__(256)
void u_reduce_kernel(const float* __restrict__ Up, float* __restrict__ U)
{
    const int idx = blockIdx.x * 256 + threadIdx.x;   // 65536 float4 elems
    const float4* src = (const float4*)Up;
    float4 s = src[idx];
#pragma unroll
    for (int kp = 1; kp < 16; ++kp) {
        float4 v = src[(size_t)kp * (M_ROWS * D_STATE / 4) + idx];
        s.x += v.x; s.y += v.y; s.z += v.z; s.w += v.w;
    }
    ((float4*)U)[idx] = s;
}

// ---------------------------------------------------------------------------
// R14: sequential scan, SHORT-CHAIN form. R13 showed 301us = ~176 cy/step:
// the precise f32 division (v_div_scale/v_rcp/v_div_fmas/v_div_fixup, ~10
// serially-dependent ops) dominated the per-step chain. Rewrite:
//   h = tanh(u+h) = 1 - 2*rcp(exp2(K*(u+h)) + 1),  K = 2*log2(e)
// with K*u precomputed during the (independent) load phase. Dependent chain
// per step = fma -> v_exp_f32 -> add -> v_rcp_f32 -> fma (5 short ops).
// Raw v_exp/v_rcp via inline asm (register-only; data-dep ordered).
// Accuracy: rcp/exp ~1ulp vs exact-div path; recurrence is contractive
// (|tanh'|<1) so error does not accumulate. Depth-2 chunk prefetch (the
// shorter chain no longer covers L2 latency at depth 1).
// ---------------------------------------------------------------------------
__global__ __launch_bounds__(64)
void scan_kernel(const float* __restrict__ U, float* __restrict__ H)
{
    const int t = threadIdx.x;
    const int b = t >> 4;
    const int s = t & 15;
    const float* u = U + (size_t)b * SEQ * D_STATE + s;
    float*       h = H + (size_t)b * SEQ * D_STATE + s;
    const float K2L = 2.8853900817779268f;   // 2*log2(e)

    float cur[8], nxt[8], nx2[8];
#pragma unroll
    for (int j = 0; j < 8; ++j) cur[j] = u[(size_t)j * D_STATE] * K2L;
#pragma unroll
    for (int j = 0; j < 8; ++j) nxt[j] = u[(size_t)(8 + j) * D_STATE];

    float hv = 0.f;
    for (int l0 = 0; l0 < SEQ; l0 += 8) {
        if (l0 + 16 < SEQ) {
#pragma unroll
            for (int j = 0; j < 8; ++j)
                nx2[j] = u[(size_t)(l0 + 16 + j) * D_STATE];
        }
#pragma unroll
        for (int j = 0; j < 8; ++j) {
            float tt = __builtin_fmaf(hv, K2L, cur[j]);      // K*(u+h)
            float e;  asm("v_exp_f32 %0, %1" : "=v"(e) : "v"(tt));
            float d = e + 1.f;
            float r;  asm("v_rcp_f32 %0, %1" : "=v"(r) : "v"(d));
            hv = __builtin_fmaf(-2.f, r, 1.f);               // 1 - 2/(e+1)
            h[(size_t)(l0 + j) * D_STATE] = hv;
        }
        // rotate + scale (independent VALU; overlaps the next chain)
#pragma unroll
        for (int j = 0; j < 8; ++j) cur[j] = nxt[j] * K2L;
#pragma unroll
        for (int j = 0; j < 8; ++j) nxt[j] = nx2[j];
    }
}

// ---------------------------------------------------------------------------
extern "C" void kernel_launch(void* const* d_in, const int* in_sizes, int n_in,
                              void* d_out, int out_size, void* d_ws, size_t ws_size,
                              hipStream_t stream)
{
    const float* x      = (const float*)d_in[0];
    const float* W_in   = (const float*)d_in[1];
    const float* b_in   = (const float*)d_in[2];
    const float* conv_w = (const float*)d_in[3];
    const float* conv_b = (const float*)d_in[4];
    const float* Amat   = (const float*)d_in[5];
    const float* Cmat   = (const float*)d_in[6];
    const float* Dp     = (const float*)d_in[7];
    const float* W_out  = (const float*)d_in[8];
    const float* b_out  = (const float*)d_in[9];
    float* out = (float*)d_out;

    // workspace layout (132.1 MB total; 136 MB proven safe)
    char* ws = (char*)d_ws;
    u16*   xbp  = (u16*)(ws);                    // 33.55 MB packed x
    u16*   Wp0  = (u16*)(ws +  33554432);        //  4.19 MB packed W_in[:, :2048]^T
    u16*   Wp1  = (u16*)(ws +  37748736);        //  4.19 MB packed W_in[:, 2048:]^T
    u16*   Wp2  = (u16*)(ws +  41943040);        //  4.19 MB packed W_out^T
    u16*   XCp  = (u16*)(ws +  46137344);        // 67.11 MB packed x_conv
    float* U    = (float*)(ws + 113246208);      //  1.05 MB
    float* H    = (float*)(ws + 114294784);      //  1.05 MB
    float* Up   = (float*)(ws + 115343360);      // 16.78 MB U partials (16x)
    u16*   XP   = (u16*)d_out;  // x_proj bf16 in d_out (67.1 MB), dead after conv

    // 1) pack inputs
    pack_x_kernel<<<dim3(16, 128), 256, 0, stream>>>(x, xbp);
    pack_w_kernel<<<dim3(16, 16), 256, 0, stream>>>(W_in, Wp0, 2 * E_DIM, 0, 16);
    pack_w_kernel<<<dim3(16, 16), 256, 0, stream>>>(W_in, Wp1, 2 * E_DIM, E_DIM, 16);
    pack_w_kernel<<<dim3(32, 8), 256, 0, stream>>>(W_out, Wp2, D_MODEL, 0, 32);

    // 2) XP = bf16(x @ W_in[:, :2048] + b_in)   (row-major, -> d_out)
    mfma_gemm<0><<<dim3(8, 64), 512, 0, stream>>>(
        xbp, Wp0, D_MODEL, E_DIM, b_in, XP, nullptr, nullptr, nullptr, nullptr, nullptr);

    // 3) XCp = packed bf16(causal_conv(XP) + conv_b)
    conv_kernel<<<dim3(32, 128), 256, 0, stream>>>(XP, conv_w, conv_b, XCp);

    // 4) U = XC @ A  (partials + reduce); 5) scan -> H
    u_part_kernel<<<dim3(16, 128), 256, 0, stream>>>(XCp, Amat, Up);
    u_reduce_kernel<<<256, 256, 0, stream>>>(Up, U);
    scan_kernel<<<1, 64, 0, stream>>>(U, H);

    // 6) XCp <- sigmoid(x @ W_in[:, 2048:] + b_in[2048:]) * (H@C^T + Dp*XCp)
    mfma_gemm<1><<<dim3(8, 64), 512, 0, stream>>>(
        xbp, Wp1, D_MODEL, 0, b_in + E_DIM, nullptr, nullptr, H, Cmat, Dp, XCp);

    // 7) out = XC @ W_out + b_out   (fp32, row-major)
    mfma_gemm<2><<<dim3(4, 64), 512, 0, stream>>>(
        XCp, Wp2, E_DIM, D_MODEL, b_out, nullptr, out, nullptr, nullptr, nullptr, nullptr);
}